// Round 1
// baseline (434.353 us; speedup 1.0000x reference)
//
#include <hip/hip_runtime.h>
#include <hip/hip_bf16.h>

typedef __hip_bfloat16 bf16;
typedef unsigned short u16;
typedef __attribute__((ext_vector_type(8))) short short8;
typedef __attribute__((ext_vector_type(4))) short s4v;
typedef __attribute__((ext_vector_type(4))) float f32x4;

#define LEAK 0.1f
#define EPS_ 1e-5f
#define MFMA(a, b, c) __builtin_amdgcn_mfma_f32_16x16x32_bf16(a, b, c, 0, 0, 0)
// N=32 C=64 T=400 V=27 S=2 IC=16 O=64 -- all inputs/outputs fp32

__device__ __forceinline__ float u2f(u16 u) { return __uint_as_float(((unsigned int)u) << 16); }
__device__ __forceinline__ u16 f2u(float f) {
  bf16 h = __float2bfloat16(f);
  u16 r;
  __builtin_memcpy(&r, &h, 2);
  return r;
}
__device__ __forceinline__ f32x4 z4() { f32x4 z = {0.f, 0.f, 0.f, 0.f}; return z; }

// ---------------------------------------------------------------------------
// K1 (MFMA): att logits. Per block: (n, 16 t-slices as 8 PAIRS). 4 waves.
// Per pair: stage y=x+pe for both slices -> qk GEMM for both slices
// -> S3 logit MFMA with the two slices K-PACKED into one full K=32 MFMA
// (slice0 in kk 0..15, slice1 in kk 16..31). 3 barriers per pair (was per
// slice). C-frags accumulate across pairs in regs; atomicAdd at block end.
// ---------------------------------------------------------------------------
__global__ __launch_bounds__(256) void k_att_mfma(
    const float* __restrict__ x, const float* __restrict__ pe,
    const float* __restrict__ W_in, const float* __restrict__ b_in,
    float* __restrict__ att)
{
  __shared__ __align__(16) u16 syT[2][32][72];   // (x+pe)^T per slice: [sl][v][c]
  __shared__ __align__(16) u16 sqkT[2][32][72];  // qk^T per slice:    [sl][v][r]
  const int tid = threadIdx.x;
  const int w = tid >> 6, lane = tid & 63;
  const int m = lane & 15, quad = lane >> 4;
  const int n = blockIdx.y, t0 = blockIdx.x * 16;
  const int s_w = w >> 1, mtu = w & 1;

  for (int i = tid; i < 2 * 32 * 72; i += 256) { syT[0][0][i] = 0; sqkT[0][0][i] = 0; }

  // persistent W_in A-frags for wave's qk row-tile (rows 16w..16w+15)
  short8 aW[2];
#pragma unroll
  for (int kf = 0; kf < 2; ++kf) {
    short8 tt;
#pragma unroll
    for (int j = 0; j < 8; ++j)
      tt[j] = (short)f2u(W_in[(16 * w + m) * 64 + 32 * kf + 8 * quad + j]);
    aW[kf] = tt;
  }
  float bb[4];
#pragma unroll
  for (int r = 0; r < 4; ++r) bb[r] = b_in[16 * w + quad * 4 + r];
  f32x4 accA0 = z4(), accA1 = z4();  // logit C-frags (nt=0,1)
  __syncthreads();

  for (int it = 0; it < 8; ++it) {
    const int t = t0 + 2 * it;  // pair covers t, t+1 (always in [0,400))
    // S1: stage y = x + pe for both slices; 54-float contiguous runs
    for (int i = tid; i < 64 * 54; i += 256) {
      int c = i / 54, r = i % 54;
      int sl = r / 27, v = r % 27;
      syT[sl][v][c] = f2u(x[((n * 64 + c) * 400 + t) * 27 + r] +
                          pe[(c * 400 + t) * 27 + r]);
    }
    __syncthreads();
    // S2: qk GEMM per slice (M-tile = wave), packed short4 epilogue with bias
#pragma unroll
    for (int sl = 0; sl < 2; ++sl) {
      f32x4 a0 = z4(), a1 = z4();
#pragma unroll
      for (int kf = 0; kf < 2; ++kf) {
        short8 b0 = *(const short8*)&syT[sl][m][32 * kf + 8 * quad];
        short8 b1 = *(const short8*)&syT[sl][16 + m][32 * kf + 8 * quad];
        a0 = MFMA(aW[kf], b0, a0);
        a1 = MFMA(aW[kf], b1, a1);
      }
#pragma unroll
      for (int nt = 0; nt < 2; ++nt) {
        f32x4 a = nt ? a1 : a0;
        int v = 16 * nt + m;
        if (v < 27) {
          s4v pk;
#pragma unroll
          for (int reg = 0; reg < 4; ++reg) pk[reg] = (short)f2u(a[reg] + bb[reg]);
          *(s4v*)&sqkT[sl][v][16 * w + quad * 4] = pk;
        }
      }
    }
    __syncthreads();
    // S3: logit accumulate, both slices K-packed into one full-K MFMA pair.
    // kk 0..15 = slice0 ic 0..15 (quad 0,1); kk 16..31 = slice1 (quad 2,3).
    {
      short8 aQ  = *(const short8*)&sqkT[quad >> 1][16 * mtu + m][16 * s_w + 8 * (quad & 1)];
      short8 bK0 = *(const short8*)&sqkT[quad >> 1][m][32 + 16 * s_w + 8 * (quad & 1)];
      short8 bK1 = *(const short8*)&sqkT[quad >> 1][16 + m][32 + 16 * s_w + 8 * (quad & 1)];
      accA0 = MFMA(aQ, bK0, accA0);
      accA1 = MFMA(aQ, bK1, accA1);
    }
    __syncthreads();
  }
  // export: rows u = 16*mtu + quad*4+reg, cols v = 16*nt + m
#pragma unroll
  for (int nt = 0; nt < 2; ++nt) {
    f32x4 a = nt ? accA1 : accA0;
#pragma unroll
    for (int reg = 0; reg < 4; ++reg) {
      int u = 16 * mtu + quad * 4 + reg, v = 16 * nt + m;
      if (u < 27 && v < 27)
        atomicAdd(&att[(n * 2 + s_w) * 729 + u * 27 + v], a[reg]);
    }
  }
}

// ---------------------------------------------------------------------------
// K1b: att = tanh(acc/6400)*alphas[s] + att0[s,u,v]   (in place)
// ---------------------------------------------------------------------------
__global__ __launch_bounds__(256) void k_att_fin(
    float* __restrict__ att, const float* __restrict__ alphas,
    const float* __restrict__ att0)
{
  int i = blockIdx.x * 256 + threadIdx.x;
  if (i >= 32 * 2 * 729) return;
  int s = (i / 729) & 1;
  int r = i % 729;
  att[i] = tanhf(att[i] * (1.f / 6400.f)) * alphas[s] + att0[s * 729 + r];
}

// ---------------------------------------------------------------------------
// K2 (MFMA fused): per block (n, 8 center t + 1 halo each side), processed as
// 5 PAIRS of slices. 4 waves; wave w owns output-channel rows [16w,16w+16).
// Per pair p (slices st=2p,2p+1; t = t0-1+st):
//   S1 stage x(both) | S2 y2=x·att(both) | S3 y3=lrelu(x+bn(Wout@y2))(both)
//   | S4 y4=lrelu(x+bn(Wff@y3))(both, 4-slot ring) | S5 two z outputs
// 4 barriers per pair (was 5 per slice). Epilogue LDS writes packed (b64).
// Weights as persistent register A-frags. LDS 55.3 KB.
// ---------------------------------------------------------------------------
__global__ __launch_bounds__(256) void k_fused_mfma(
    const float* __restrict__ x, const float* __restrict__ att,
    const float* __restrict__ W_out, const float* __restrict__ b_out,
    const float* __restrict__ g_out, const float* __restrict__ be_out,
    const float* __restrict__ m_out, const float* __restrict__ v_out,
    const float* __restrict__ W_ff, const float* __restrict__ b_ff,
    const float* __restrict__ g_ff, const float* __restrict__ be_ff,
    const float* __restrict__ m_ff, const float* __restrict__ v_ff,
    const float* __restrict__ W_t, const float* __restrict__ b_t,
    const float* __restrict__ g_t, const float* __restrict__ be_t,
    const float* __restrict__ m_t, const float* __restrict__ v_t,
    float* __restrict__ out)
{
  __shared__ __align__(16) u16 sx[2][64][40];    // x bf16 [sl][c][u]; cols 27..39 zero
  __shared__ __align__(16) u16 sy2[2][32][136];  // y2^T [sl][v][s*64+c]; rows 27..31 zero
  __shared__ __align__(16) u16 sy3[2][32][72];   // y3^T [sl][v][c];      rows 27..31 zero
  __shared__ __align__(16) u16 sy4[4][32][72];   // y4^T ring [st%4][v][i]; rows 27..31 zero
  const int tid = threadIdx.x;
  const int w = tid >> 6, lane = tid & 63;
  const int m = lane & 15, quad = lane >> 4;
  const int n = blockIdx.y, t0 = blockIdx.x * 8;

  for (int i = tid; i < 2 * 64 * 40; i += 256) sx[0][0][i] = 0;
  for (int i = tid; i < 2 * 32 * 136; i += 256) sy2[0][0][i] = 0;
  for (int i = tid; i < 2 * 32 * 72; i += 256) sy3[0][0][i] = 0;
  for (int i = tid; i < 4 * 32 * 72; i += 256) sy4[0][0][i] = 0;

  // persistent weight A-frags (rows o = 16w + m)
  short8 aWo[4], aWf[2], aWt[6], bAtt[4];
#pragma unroll
  for (int kf = 0; kf < 4; ++kf) {
    short8 tt;
#pragma unroll
    for (int j = 0; j < 8; ++j)
      tt[j] = (short)f2u(W_out[(16 * w + m) * 128 + 32 * kf + 8 * quad + j]);
    aWo[kf] = tt;
  }
#pragma unroll
  for (int kf = 0; kf < 2; ++kf) {
    short8 tt;
#pragma unroll
    for (int j = 0; j < 8; ++j)
      tt[j] = (short)f2u(W_ff[(16 * w + m) * 64 + 32 * kf + 8 * quad + j]);
    aWf[kf] = tt;
  }
#pragma unroll
  for (int kf = 0; kf < 6; ++kf) {  // k = dt*64 + i
    short8 tt;
    int dt = kf >> 1;
#pragma unroll
    for (int j = 0; j < 8; ++j) {
      int ii = 32 * (kf & 1) + 8 * quad + j;
      tt[j] = (short)f2u(W_t[((16 * w + m) * 64 + ii) * 3 + dt]);
    }
    aWt[kf] = tt;
  }
#pragma unroll
  for (int s = 0; s < 2; ++s)
#pragma unroll
    for (int nt = 0; nt < 2; ++nt) {
      short8 tt;
#pragma unroll
      for (int j = 0; j < 8; ++j) {
        int u = 8 * quad + j, v = 16 * nt + m;
        tt[j] = (u < 27 && v < 27) ? (short)f2u(att[(n * 2 + s) * 729 + u * 27 + v]) : (short)0;
      }
      bAtt[s * 2 + nt] = tt;
    }
  // per-lane BN constants for rows o' = 16w + quad*4 + reg
  float Ao[4], Bo[4], Af[4], Bf[4], At[4], Bt[4];
#pragma unroll
  for (int reg = 0; reg < 4; ++reg) {
    int o = 16 * w + quad * 4 + reg;
    float sc;
    sc = g_out[o] * rsqrtf(v_out[o] + EPS_); Ao[reg] = sc; Bo[reg] = (b_out[o] - m_out[o]) * sc + be_out[o];
    sc = g_ff[o] * rsqrtf(v_ff[o] + EPS_);   Af[reg] = sc; Bf[reg] = (b_ff[o] - m_ff[o]) * sc + be_ff[o];
    sc = g_t[o] * rsqrtf(v_t[o] + EPS_);     At[reg] = sc; Bt[reg] = (b_t[o] - m_t[o]) * sc + be_t[o];
  }
  __syncthreads();

  for (int p = 0; p < 5; ++p) {
    const int tA = t0 - 1 + 2 * p;  // slice pair: tA, tA+1
    const bool val0 = (tA >= 0) && (tA < 400);
    const bool val1 = (tA + 1 >= 0) && (tA + 1 < 400);
    // S1: stage x for both slices (54-float contiguous runs when both valid)
    if (val0 && val1) {
      for (int i = tid; i < 64 * 54; i += 256) {
        int c = i / 54, r = i % 54;
        sx[r / 27][c][r % 27] = f2u(x[((n * 64 + c) * 400 + tA) * 27 + r]);
      }
    } else {
#pragma unroll
      for (int sl = 0; sl < 2; ++sl) {
        if (!(sl ? val1 : val0)) continue;
        int t = tA + sl;
        for (int i = tid; i < 1728; i += 256) {
          int c = i / 27, u = i % 27;
          sx[sl][c][u] = f2u(x[((n * 64 + c) * 400 + t) * 27 + u]);
        }
      }
    }
    __syncthreads();
    // S2: y2 = x·att (both slices), packed epilogue
#pragma unroll
    for (int sl = 0; sl < 2; ++sl) {
      if (!(sl ? val1 : val0)) continue;
      short8 ax = *(const short8*)&sx[sl][16 * w + m][8 * quad];
      f32x4 acc[4];
#pragma unroll
      for (int f = 0; f < 4; ++f) acc[f] = MFMA(ax, bAtt[f], z4());
#pragma unroll
      for (int s = 0; s < 2; ++s)
#pragma unroll
        for (int nt = 0; nt < 2; ++nt) {
          int v = 16 * nt + m;
          if (v < 27) {
            f32x4 a = acc[s * 2 + nt];
            s4v pk;
#pragma unroll
            for (int reg = 0; reg < 4; ++reg) pk[reg] = (short)f2u(a[reg]);
            *(s4v*)&sy2[sl][v][s * 64 + 16 * w + quad * 4] = pk;
          }
        }
    }
    __syncthreads();
    // S3: y3 = lrelu(x + bn(W_out@y2)) (both slices)
#pragma unroll
    for (int sl = 0; sl < 2; ++sl) {
      if (!(sl ? val1 : val0)) continue;
      f32x4 a0 = z4(), a1 = z4();
#pragma unroll
      for (int kf = 0; kf < 4; ++kf) {
        short8 b0 = *(const short8*)&sy2[sl][m][32 * kf + 8 * quad];
        short8 b1 = *(const short8*)&sy2[sl][16 + m][32 * kf + 8 * quad];
        a0 = MFMA(aWo[kf], b0, a0);
        a1 = MFMA(aWo[kf], b1, a1);
      }
#pragma unroll
      for (int nt = 0; nt < 2; ++nt) {
        f32x4 a = nt ? a1 : a0;
        int v = 16 * nt + m;
        if (v < 27) {
          s4v pk;
#pragma unroll
          for (int reg = 0; reg < 4; ++reg) {
            int o = 16 * w + quad * 4 + reg;
            float r = u2f(sx[sl][o][v]) + a[reg] * Ao[reg] + Bo[reg];
            pk[reg] = (short)f2u((r >= 0.f) ? r : LEAK * r);
          }
          *(s4v*)&sy3[sl][v][16 * w + quad * 4] = pk;
        }
      }
    }
    __syncthreads();
    // S4: y4 = lrelu(x + bn(W_ff@y3)) into 4-slot ring (both slices)
#pragma unroll
    for (int sl = 0; sl < 2; ++sl) {
      int st = 2 * p + sl;
      int slot = st & 3;
      if (sl ? val1 : val0) {
        f32x4 a0 = z4(), a1 = z4();
#pragma unroll
        for (int kf = 0; kf < 2; ++kf) {
          short8 b0 = *(const short8*)&sy3[sl][m][32 * kf + 8 * quad];
          short8 b1 = *(const short8*)&sy3[sl][16 + m][32 * kf + 8 * quad];
          a0 = MFMA(aWf[kf], b0, a0);
          a1 = MFMA(aWf[kf], b1, a1);
        }
#pragma unroll
        for (int nt = 0; nt < 2; ++nt) {
          f32x4 a = nt ? a1 : a0;
          int v = 16 * nt + m;
          if (v < 27) {
            s4v pk;
#pragma unroll
            for (int reg = 0; reg < 4; ++reg) {
              int o = 16 * w + quad * 4 + reg;
              float r = u2f(sx[sl][o][v]) + a[reg] * Af[reg] + Bf[reg];
              pk[reg] = (short)f2u((r >= 0.f) ? r : LEAK * r);
            }
            *(s4v*)&sy4[slot][v][16 * w + quad * 4] = pk;
          }
        }
      } else {
        s4v zz = {0, 0, 0, 0};
        for (int i = tid; i < 576; i += 256)
          ((s4v*)&sy4[slot][0][0])[i] = zz;
      }
    }
    __syncthreads();
    // S5: two outputs per pair, centers st_c = 2p-1, 2p (t_out = t0+st_c-1)
    if (p >= 1) {
#pragma unroll
      for (int cc = 0; cc < 2; ++cc) {
        int st_c = 2 * p - 1 + cc;
        int t_out = t0 + st_c - 1;
        f32x4 a0 = z4(), a1 = z4();
#pragma unroll
        for (int kf = 0; kf < 6; ++kf) {
          int slot = (st_c - 1 + (kf >> 1)) & 3;
          int col = 32 * (kf & 1) + 8 * quad;
          short8 b0 = *(const short8*)&sy4[slot][m][col];
          short8 b1 = *(const short8*)&sy4[slot][16 + m][col];
          a0 = MFMA(aWt[kf], b0, a0);
          a1 = MFMA(aWt[kf], b1, a1);
        }
#pragma unroll
        for (int nt = 0; nt < 2; ++nt) {
          f32x4 a = nt ? a1 : a0;
          int v = 16 * nt + m;
          if (v < 27) {
#pragma unroll
            for (int reg = 0; reg < 4; ++reg) {
              int o = 16 * w + quad * 4 + reg;
              float r = u2f(sy4[st_c & 3][v][o]) + a[reg] * At[reg] + Bt[reg];
              out[((n * 64 + o) * 400 + t_out) * 27 + v] = (r >= 0.f) ? r : LEAK * r;
            }
          }
        }
      }
    }
  }
}

// ---------------------------------------------------------------------------
extern "C" void kernel_launch(void* const* d_in, const int* in_sizes, int n_in,
                              void* d_out, int out_size, void* d_ws, size_t ws_size,
                              hipStream_t stream)
{
  const float* x      = (const float*)d_in[0];
  const float* pe     = (const float*)d_in[1];
  const float* W_in   = (const float*)d_in[2];
  const float* b_in   = (const float*)d_in[3];
  const float* alphas = (const float*)d_in[4];
  const float* att0   = (const float*)d_in[5];
  const float* W_out  = (const float*)d_in[6];
  const float* b_out  = (const float*)d_in[7];
  const float* g_out  = (const float*)d_in[8];
  const float* be_out = (const float*)d_in[9];
  const float* m_out  = (const float*)d_in[10];
  const float* v_out  = (const float*)d_in[11];
  const float* W_ff   = (const float*)d_in[12];
  const float* b_ff   = (const float*)d_in[13];
  const float* g_ff   = (const float*)d_in[14];
  const float* be_ff  = (const float*)d_in[15];
  const float* m_ff   = (const float*)d_in[16];
  const float* v_ff   = (const float*)d_in[17];
  const float* W_t    = (const float*)d_in[18];
  const float* b_t    = (const float*)d_in[19];
  const float* g_t    = (const float*)d_in[20];
  const float* be_t   = (const float*)d_in[21];
  const float* m_t    = (const float*)d_in[22];
  const float* v_t    = (const float*)d_in[23];

  float* att = (float*)d_ws;  // 32*2*729 floats = 186 KB — only ws use

  hipMemsetAsync(att, 0, 32 * 2 * 729 * sizeof(float), stream);
  k_att_mfma<<<dim3(25, 32), 256, 0, stream>>>(x, pe, W_in, b_in, att);
  k_att_fin<<<dim3((32 * 2 * 729 + 255) / 256), 256, 0, stream>>>(att, alphas, att0);
  k_fused_mfma<<<dim3(50, 32), 256, 0, stream>>>(
      x, att,
      W_out, b_out, g_out, be_out, m_out, v_out,
      W_ff, b_ff, g_ff, be_ff, m_ff, v_ff,
      W_t, b_t, g_t, be_t, m_t, v_t,
      (float*)d_out);
}